// Round 4
// baseline (19530.858 us; speedup 1.0000x reference)
//
#include <hip/hip_runtime.h>
#include <hip/hip_bf16.h>

// STN_RNN: B=32, T=4096, IN=1, H=512, gates=2048, k=0.5 blend.
// R8: per-wave pipelined exchange (no global arrival barrier).
// Structural fact: consumer thread (jq,ks)'s k-range [ks*64, ks*64+64) lies
// entirely in publisher slice ks, and ks == wave index. So wave w only needs
// slice w: each wave polls its own 64 tagged words and starts its dot as soon
// as ITS slice arrives (slice arrival jitter overlaps other waves' compute).
// A WG's 256 gate cols are exactly the 4 gates of its own 64 units, so wave 0
// alone does reduce + cell (h/c state in REGISTERS) + tagged publish right
// after barrier B; waves 1-7 skip straight to polling t+1, fully overlapping
// the producer-side cell. ONE barrier per step.
// parts[] double-buffered by t&1: slot reuse at t+2 is ordered behind wave-0's
// reads via the tag chain (publish(t+2) <- producer B(t+1) <- its detect(t+1)
// <- our publish(t+1) <- our parts reads at t).
// Weights stay register-resident bf16-packed (128 u32/thread).

#define NBATCH 32
#define NT     4096
#define NH     512
#define UNITS  64

// ws byte offsets
#define FLAG_OFF  0u
#define BIAS_OFF  4096u      // 2048 f32
#define WIH_OFF   12288u     // 2048 f32
#define XF_OFF    20480u     // 131072 f32 = 512 KiB
#define HBUF_OFF  544768u    // 2*32*512 x 8B tagged = 256 KiB = 65536 dwords
#define WP_OFF    806912u    // 8 slices x 32 r4 x 512 tid x 4 u32 = 2 MiB

#define HBUF_DWORDS 65536

__device__ __forceinline__ float bf2f(unsigned short u) {
    union { unsigned int i; float f; } v; v.i = ((unsigned int)u) << 16; return v.f;
}
__device__ __forceinline__ unsigned short f2bf_rne(float f) {
    union { unsigned int i; float f; } v; v.f = f;
    return (unsigned short)((v.i + 0x7fffu + ((v.i >> 16) & 1u)) >> 16);
}
__device__ __forceinline__ float lo_bf(unsigned int u) {
    union { unsigned int i; float f; } v; v.i = u << 16; return v.f;
}
__device__ __forceinline__ float hi_bf(unsigned int u) {
    union { unsigned int i; float f; } v; v.i = u & 0xffff0000u; return v.f;
}
__device__ __forceinline__ float sigm(float x) {
    return 1.0f / (1.0f + __expf(-x));
}
__device__ __forceinline__ float tanh_fast(float x) {
    float e = __expf(-2.0f * fabsf(x));
    float r = (1.0f - e) / (1.0f + e);
    return copysignf(r, x);
}
// col = wg*256 + (gate*64 + u)  ->  row = gate*512 + wg*64 + u
__device__ __forceinline__ int col2row(int col) {
    int wg = col >> 8, r = col & 255, g = (r >> 6) & 3, u = r & 63;
    return g * 512 + wg * 64 + u;
}

// ---- dtype detect (bf16 vs f32) ----
__global__ void prep_detect(const unsigned short* __restrict__ wih_u,
                            int* __restrict__ flagp) {
    __shared__ int cnt;
    if (threadIdx.x == 0) cnt = 0;
    __syncthreads();
    int local = 0;
    for (int i = threadIdx.x; i < 1024; i += 256) {
        float v = bf2f(wih_u[2 * i]);
        if (fabsf(v) <= 0.0625f) local++;
    }
    atomicAdd(&cnt, local);
    __syncthreads();
    if (threadIdx.x == 0) *flagp = (cnt >= 1000) ? 1 : 0;
}

// ---- build packed per-thread weight image WP, bias, W_ih, x; zero hbuf ----
// WP dword index = wg*65536 + r4*2048 + tid*4 + j   (r = r4*4+j, c=r>>5, k2=r&31)
// value = pack_bf16( W[row(col)][k0], W[row(col)][k0+1] ), col=wg*256+jq*4+c,
// k0 = ks*64 + 2*k2, jq=tid&63, ks=tid>>6.
__global__ void prep_conv(const void* __restrict__ x,
                          const void* __restrict__ Wih,
                          const void* __restrict__ Whh,
                          const void* __restrict__ bih,
                          const void* __restrict__ bhh,
                          const int* __restrict__ flagp,
                          unsigned int* __restrict__ WP,
                          float* __restrict__ bias_p,
                          float* __restrict__ wih_p,
                          float* __restrict__ Xf,
                          unsigned int* __restrict__ hbuf_z) {
    int idx = blockIdx.x * blockDim.x + threadIdx.x;   // 524288
    int isbf = *flagp;

    {
        int wg  = idx >> 16;
        int rem = idx & 65535;
        int r4  = rem >> 11;
        int tid = (rem >> 2) & 511;
        int j   = rem & 3;
        int r   = r4 * 4 + j;
        int c   = r >> 5;
        int k2  = r & 31;
        int jq  = tid & 63;
        int ks  = tid >> 6;
        int col = wg * 256 + jq * 4 + c;
        int row = col2row(col);
        int k0  = ks * 64 + 2 * k2;
        unsigned short lo, hi;
        if (isbf) {
            lo = ((const unsigned short*)Whh)[(size_t)row * 512 + k0];
            hi = ((const unsigned short*)Whh)[(size_t)row * 512 + k0 + 1];
        } else {
            lo = f2bf_rne(((const float*)Whh)[(size_t)row * 512 + k0]);
            hi = f2bf_rne(((const float*)Whh)[(size_t)row * 512 + k0 + 1]);
        }
        WP[idx] = (unsigned int)lo | ((unsigned int)hi << 16);
    }

    // zero the tagged h double-buffer (exactly HBUF_DWORDS dwords) so
    // stale tags from a previous launch can never match.
    if (idx < HBUF_DWORDS) hbuf_z[idx] = 0u;

    if (idx < 2048) {
        int col = idx;
        int row = col2row(col);
        float bi, bh, wi;
        if (isbf) {
            bi = bf2f(((const unsigned short*)bih)[row]);
            bh = bf2f(((const unsigned short*)bhh)[row]);
            wi = bf2f(((const unsigned short*)Wih)[row]);
        } else {
            bi = ((const float*)bih)[row];
            bh = ((const float*)bhh)[row];
            wi = ((const float*)Wih)[row];
        }
        bias_p[col] = bi + bh;
        wih_p[col]  = wi;
    }
    if (idx < NBATCH * NT) {
        Xf[idx] = isbf ? bf2f(((const unsigned short*)x)[idx])
                       : ((const float*)x)[idx];
    }
}

__global__ void __launch_bounds__(512, 2) rnn_kernel(
    const float* __restrict__ Xf,
    const unsigned int* __restrict__ WP,
    const float* __restrict__ bias_p,
    const float* __restrict__ wih_p,
    unsigned long long* __restrict__ hbuf,
    const int* __restrict__ flagp,
    void* __restrict__ out)
{
    const int tid = threadIdx.x;
    const int bid = blockIdx.x;
    const int b   = bid & 31;
    const int wg  = bid >> 5;
    const int isbf = *flagp;

    __shared__ float hsh[512];          // per-wave private 64-float rows
    __shared__ float xsh[NT];           // 16 KiB: whole x row for this batch
    __shared__ float parts[2][8][256];  // double-buffered by t&1

    const int l = tid & 63;   // lane within wave
    const int w = tid >> 6;   // wave index == k-slice index

    // ---- stage x row in LDS (visible at first barrier B, before first use) ----
    for (int i = tid; i < NT; i += 512) xsh[i] = Xf[(size_t)b * NT + i];

    // ---- load register-resident packed weights: 128 u32 = 256 bf16 ----
    unsigned int wreg[128];
    {
        const uint4* wp = (const uint4*)WP + (size_t)wg * 16384 + tid;
        #pragma unroll
        for (int r4 = 0; r4 < 32; ++r4) {
            uint4 v = wp[(size_t)r4 * 512];
            wreg[r4 * 4 + 0] = v.x;
            wreg[r4 * 4 + 1] = v.y;
            wreg[r4 * 4 + 2] = v.z;
            wreg[r4 * 4 + 3] = v.w;
        }
    }

    // ---- wave-0 constants: bias/wih for this WG's 64 units x 4 gates ----
    float bias4[4] = {0.f, 0.f, 0.f, 0.f};
    float wih4[4]  = {0.f, 0.f, 0.f, 0.f};
    if (tid < 64) {
        #pragma unroll
        for (int g = 0; g < 4; ++g) {
            bias4[g] = bias_p[wg * 256 + g * 64 + tid];
            wih4[g]  = wih_p[wg * 256 + g * 64 + tid];
        }
    }
    float creg = 0.0f, hreg = 0.0f;   // wave-0 per-lane LSTM state

    unsigned short* outb_u = (unsigned short*)out + (size_t)b * NT * NH;
    float*          outb_f = (float*)out + (size_t)b * NT * NH;

    unsigned int broken = 0;

    for (int t = 0; t < NT; ++t) {
        // ---- P: wave w acquires slice w only (its own k-range) ----
        if (t == 0) {
            hsh[tid] = 0.0f;
        } else {
            const unsigned long long* hin =
                hbuf + (((t & 1) * NBATCH + b) << 9) + tid;
            unsigned long long v = 0;
            if (!broken) {
                int g = 0;
                for (;;) {
                    v = __hip_atomic_load(hin, __ATOMIC_RELAXED,
                                          __HIP_MEMORY_SCOPE_AGENT);
                    if (__all((unsigned int)(v >> 32) == (unsigned int)t)) break;
                    __builtin_amdgcn_s_sleep(1);
                    if (++g > 2000000) { broken = 1; break; }
                }
            }
            union { unsigned int u; float f; } cv; cv.u = (unsigned int)v;
            hsh[tid] = cv.f;   // wave-private row; compiler orders via lgkmcnt
        }

        // ---- D: dot from registers, 4 cols x 64 k, k-range = slice w ----
        float a0 = 0.f, a1 = 0.f, a2 = 0.f, a3 = 0.f;
        float c0 = 0.f, c1 = 0.f, c2 = 0.f, c3 = 0.f;
        const float* hq = hsh + w * 64;
        #pragma unroll
        for (int k2 = 0; k2 < 32; ++k2) {
            float h0 = hq[2 * k2];
            float h1 = hq[2 * k2 + 1];
            unsigned int u0 = wreg[k2];
            unsigned int u1 = wreg[32 + k2];
            unsigned int u2 = wreg[64 + k2];
            unsigned int u3 = wreg[96 + k2];
            a0 = fmaf(h0, lo_bf(u0), a0);  c0 = fmaf(h1, hi_bf(u0), c0);
            a1 = fmaf(h0, lo_bf(u1), a1);  c1 = fmaf(h1, hi_bf(u1), c1);
            a2 = fmaf(h0, lo_bf(u2), a2);  c2 = fmaf(h1, hi_bf(u2), c2);
            a3 = fmaf(h0, lo_bf(u3), a3);  c3 = fmaf(h1, hi_bf(u3), c3);
        }
        a0 += c0; a1 += c1; a2 += c2; a3 += c3;
        *(float4*)&parts[t & 1][w][l * 4] = make_float4(a0, a1, a2, a3);
        __syncthreads();                       // barrier B (the only one)

        // ---- R+C: wave 0 reduces its WG's 256 cols, runs cell, publishes ----
        if (tid < 64) {
            const float xt = xsh[t];
            float gsum[4];
            #pragma unroll
            for (int g = 0; g < 4; ++g) {
                float acc = parts[t & 1][0][g * 64 + tid];
                #pragma unroll
                for (int s = 1; s < 8; ++s) acc += parts[t & 1][s][g * 64 + tid];
                gsum[g] = acc + bias4[g] + xt * wih4[g];
            }
            float ig = sigm(gsum[0]);
            float fg = sigm(gsum[1]);
            float gg = tanh_fast(gsum[2]);
            float og = sigm(gsum[3]);
            float cnew = fg * creg + ig * gg;
            float hnew = og * tanh_fast(cnew);
            float cb = 0.5f * (creg + cnew);
            float hb = 0.5f * (hreg + hnew);
            creg = cb; hreg = hb;
            // single 8B tagged store: data + signal in one coherence leg
            union { float f; unsigned int u; } hv; hv.f = hb;
            unsigned long long pkt =
                ((unsigned long long)(unsigned int)(t + 1) << 32) | hv.u;
            unsigned long long* hout =
                hbuf + ((((t + 1) & 1) * NBATCH + b) << 9) + wg * 64 + tid;
            __hip_atomic_store(hout, pkt, __ATOMIC_RELAXED,
                               __HIP_MEMORY_SCOPE_AGENT);
            if (isbf) outb_u[(size_t)t * NH + wg * 64 + tid] = f2bf_rne(hb);
            else      outb_f[(size_t)t * NH + wg * 64 + tid] = hb;
        }
        // no second barrier: waves 1-7 proceed straight to P(t+1).
        // parts hazard is covered by the t&1 double buffer + tag chain;
        // hsh rows are wave-private; xsh is read-only.
    }

    // ---- final_state [h | c] from wave-0 registers ----
    if (tid < 64) {
        size_t fsbase = (size_t)NBATCH * NT * NH + (size_t)b * (2 * NH);
        if (isbf) {
            ((unsigned short*)out)[fsbase + wg * 64 + tid]       = f2bf_rne(hreg);
            ((unsigned short*)out)[fsbase + 512 + wg * 64 + tid] = f2bf_rne(creg);
        } else {
            ((float*)out)[fsbase + wg * 64 + tid]       = hreg;
            ((float*)out)[fsbase + 512 + wg * 64 + tid] = creg;
        }
    }
}

extern "C" void kernel_launch(void* const* d_in, const int* in_sizes, int n_in,
                              void* d_out, int out_size, void* d_ws, size_t ws_size,
                              hipStream_t stream) {
    const void* x   = d_in[0];
    const void* Wih = d_in[1];
    const void* Whh = d_in[2];
    const void* bih = d_in[3];
    const void* bhh = d_in[4];

    char* ws = (char*)d_ws;
    int* flagp          = (int*)(ws + FLAG_OFF);
    float* bias_p       = (float*)(ws + BIAS_OFF);
    float* wih_p        = (float*)(ws + WIH_OFF);
    float* Xf           = (float*)(ws + XF_OFF);
    unsigned long long* hbuf = (unsigned long long*)(ws + HBUF_OFF);
    unsigned int* WP    = (unsigned int*)(ws + WP_OFF);

    prep_detect<<<1, 256, 0, stream>>>((const unsigned short*)Wih, flagp);
    prep_conv<<<2048, 256, 0, stream>>>(x, Wih, Whh, bih, bhh, flagp,
                                        WP, bias_p, wih_p, Xf,
                                        (unsigned int*)hbuf);
    rnn_kernel<<<256, 512, 0, stream>>>(Xf, WP, bias_p, wih_p, hbuf,
                                        flagp, d_out);
}